// Round 6
// baseline (196.719 us; speedup 1.0000x reference)
//
#include <hip/hip_runtime.h>

#define NB 8
#define NN 100000
#define NC 90
#define SCORE_THR 0.05f
#define IOU_THR 0.5f
#define MAX_DET 100
#define PRE_NMS_K 512
#define NEGV -1000000000.0f
#define T0 0.9925f
#define CAP 1024
#define NBC (NB * NC)
#define CNT_STRIDE 16   // u32 words per counter (64B line padding)
#define CHUNK 1024
#define NCHUNK 98       // ceil(100000/1024)
#define LCAP 32
// Exact: RN(inter/denom) > 0.5f  <=>  (double)inter > (0.5+2^-26)*(double)denom
// (denom has 24-bit mantissa; (1+2^-25) has 26 bits; product <= 50 bits -> exact in f64)
#define IOU_CMP_C 0x1.0000008p-1

typedef float f32x4 __attribute__((ext_vector_type(4)));

__device__ __forceinline__ unsigned ordf(float s) {
    unsigned u = __float_as_uint(s);
    return (u & 0x80000000u) ? ~u : (u | 0x80000000u);
}
__device__ __forceinline__ float deordf(unsigned o) {
    return (o & 0x80000000u) ? __uint_as_float(o ^ 0x80000000u) : __uint_as_float(~o);
}
__device__ __forceinline__ unsigned long long mkkey(float s, unsigned idx) {
    return ((unsigned long long)ordf(s) << 32) | (unsigned long long)(0xFFFFFFFFu - idx);
}

// ---------------- zero counters + overflow flags ----------------
__global__ __launch_bounds__(256) void k_zero(uint4* __restrict__ cnt4, uint4* __restrict__ ovf4) {
    unsigned i = blockIdx.x * 256u + threadIdx.x;
    if (i < (NBC * CNT_STRIDE) / 4) cnt4[i] = make_uint4(0u, 0u, 0u, 0u);
    if (i < NBC / 4) ovf4[i] = make_uint4(0u, 0u, 0u, 0u);
}

// ---------------- Pass 1: streaming scan (4-deep nontemporal loads), per-class LDS staging ----------------
__global__ __launch_bounds__(512) void k_collect(const float* __restrict__ scores,
                                                 unsigned* __restrict__ cnt,
                                                 unsigned* __restrict__ ovf,
                                                 unsigned long long* __restrict__ buf) {
    __shared__ unsigned long long lst[NC][LCAP + 1];
    __shared__ unsigned lcnt[NC];
    int b = blockIdx.x / NCHUNK;
    int chunk = blockIdx.x - b * NCHUNK;
    int n0 = chunk * CHUNK;
    int ncount = NN - n0; if (ncount > CHUNK) ncount = CHUNK;
    int nf4 = (ncount * NC) >> 2;            // ncount*90 always divisible by 4
    const f32x4* base4 = reinterpret_cast<const f32x4*>(scores + ((size_t)b * NN + n0) * NC);

    for (int i = threadIdx.x; i < NC; i += 512) lcnt[i] = 0u;
    __syncthreads();

    // 4 independent 16B loads in flight per thread per iteration (memory-level parallelism)
    for (int i0 = (int)threadIdx.x; i0 < nf4; i0 += 2048) {
        f32x4 v[4];
        #pragma unroll
        for (int k = 0; k < 4; ++k) {
            int idx = i0 + k * 512;
            if (idx < nf4) v[k] = __builtin_nontemporal_load(base4 + idx);
        }
        #pragma unroll
        for (int k = 0; k < 4; ++k) {
            int idx = i0 + k * 512;
            if (idx < nf4) {
                #pragma unroll
                for (int e = 0; e < 4; ++e) {
                    float s = v[k][e];
                    if (s >= T0) {
                        int local = 4 * idx + e;
                        int c = local % NC;
                        int n = n0 + local / NC;
                        unsigned slot = atomicAdd(&lcnt[c], 1u);
                        if (slot < LCAP) lst[c][slot] = mkkey(s, (unsigned)n);
                        else atomicOr(&ovf[b * NC + c], 1u);   // ~never
                    }
                }
            }
        }
    }
    __syncthreads();

    if (threadIdx.x < NC) {
        int c = threadIdx.x;
        unsigned k = lcnt[c]; if (k > LCAP) k = LCAP;
        if (k) {
            int bc = b * NC + c;
            unsigned basep = atomicAdd(&cnt[(size_t)bc * CNT_STRIDE], k);
            if (basep + k > CAP) atomicOr(&ovf[bc], 1u);
            unsigned lim = (basep + k <= CAP) ? k : (basep < CAP ? CAP - basep : 0u);
            for (unsigned j = 0; j < lim; ++j)
                buf[(size_t)bc * CAP + basep + j] = lst[c][j];
        }
    }
}

// ---------------- Fused: (rebuild-if-bad) -> bitonic sort 1024 -> pointer-walk NMS (wave 0) ----------------
__global__ __launch_bounds__(256) void k_sortnms(const float* __restrict__ scores,
                                                 const float* __restrict__ boxes,
                                                 const unsigned* __restrict__ cnt,
                                                 const unsigned* __restrict__ ovf,
                                                 const unsigned long long* __restrict__ buf,
                                                 float* __restrict__ sel_score,
                                                 float4* __restrict__ sel_box) {
    #pragma clang fp contract(off)
    int bc = blockIdx.x;
    int tid = threadIdx.x;
    __shared__ unsigned long long keys[CAP];
    // box/area (good path, post-sort) overlay hist (bad path, pre-sort) — never live together
    __shared__ __align__(16) unsigned char gmem[PRE_NMS_K * 16 + PRE_NMS_K * 4];
    float4* box_lds = (float4*)gmem;
    float* area_lds = (float*)(gmem + PRE_NMS_K * 16);
    unsigned* hist = (unsigned*)gmem;
    __shared__ unsigned s_lcnt;
    __shared__ float s_cut;

    unsigned K = cnt[(size_t)bc * CNT_STRIDE];
    bool bad = (ovf[bc] != 0u) || (K < (unsigned)PRE_NMS_K) || (K > CAP);

    if (bad) {
        // exact rebuild directly into LDS (never fires for this input)
        int b = bc / NC, c = bc - (bc / NC) * NC;
        for (int i = tid; i < 1024; i += 256) hist[i] = 0u;
        if (tid == 0) s_lcnt = 0u;
        __syncthreads();
        for (int n = tid; n < NN; n += 256) {
            float s = scores[((size_t)b * NN + n) * NC + c];
            if (s >= SCORE_THR) {
                int bin = (int)(s * 1024.0f);
                bin = bin < 0 ? 0 : (bin > 1023 ? 1023 : bin);
                atomicAdd(&hist[bin], 1u);
            }
        }
        __syncthreads();
        if (tid == 0) {
            unsigned tot = 0;
            for (int i = 0; i < 1024; ++i) tot += hist[i];
            unsigned target = tot < (unsigned)PRE_NMS_K ? tot : (unsigned)PRE_NMS_K;
            float cut = 3.0e38f;
            if (target > 0) {
                unsigned cum = 0; int t = 1023;
                for (; t >= 0; --t) { cum += hist[t]; if (cum >= target) break; }
                cut = (float)t / 1024.0f;
                if (cut < SCORE_THR) cut = SCORE_THR;
            }
            s_cut = cut;
        }
        __syncthreads();
        float cut = s_cut;
        for (int n = tid; n < NN; n += 256) {
            float s = scores[((size_t)b * NN + n) * NC + c];
            if (s >= SCORE_THR && s >= cut) {
                unsigned slot = atomicAdd(&s_lcnt, 1u);
                if (slot < CAP) keys[slot] = mkkey(s, (unsigned)n);
            }
        }
        __syncthreads();
        K = s_lcnt; if (K > CAP) K = CAP;
        for (unsigned i = K + tid; i < CAP; i += 256) keys[i] = 0ULL;
        __syncthreads();
    } else {
        for (unsigned i = tid; i < CAP; i += 256)
            keys[i] = (i < K) ? buf[(size_t)bc * CAP + i] : 0ULL;
    }

    // bitonic sort, descending. Barrier only when data crosses 64-element (wave-owned)
    // blocks: j<64 stages are wave-synchronous (wave64 lockstep, in-order LDS pipe).
    bool prev_big = false;
    for (unsigned k2 = 2; k2 <= CAP; k2 <<= 1) {
        for (unsigned j = k2 >> 1; j; j >>= 1) {
            bool big = (j >= 64);
            if (big || prev_big) __syncthreads();
            #pragma unroll
            for (unsigned ii = 0; ii < 4; ++ii) {
                unsigned i = tid + ii * 256u;
                unsigned ixj = i ^ j;
                if (ixj > i) {
                    unsigned long long a = keys[i], bv = keys[ixj];
                    bool desc = ((i & k2) == 0);
                    if (desc ? (a < bv) : (a > bv)) { keys[i] = bv; keys[ixj] = a; }
                }
            }
            prev_big = big;
        }
    }
    __syncthreads();

    // gather boxes + areas for the (sorted) top-512
    int b = bc / NC;
    for (int r = tid; r < PRE_NMS_K; r += 256) {
        unsigned long long key = keys[r];
        float4 bx = make_float4(0.f, 0.f, 0.f, 0.f);
        if (key != 0ULL) {
            unsigned n = 0xFFFFFFFFu - (unsigned)(key & 0xFFFFFFFFu);
            bx = *reinterpret_cast<const float4*>(boxes + ((size_t)b * NN + n) * 4);
        }
        box_lds[r] = bx;
        area_lds[r] = (bx.z - bx.x) * (bx.w - bx.y);
    }
    __syncthreads();

    // NMS on wave 0: sorted keys => winner = first alive index (pointer walk via ballot)
    if (tid < 64) {
        int lane = tid;
        float y1[8], x1[8], y2[8], x2[8], ar[8];
        unsigned alive = 0u;                 // 8 candidates per lane, contiguous: r = lane*8+k
        #pragma unroll
        for (int k = 0; k < 8; ++k) {
            int r = lane * 8 + k;
            float4 bx = box_lds[r];
            y1[k] = bx.x; x1[k] = bx.y; y2[k] = bx.z; x2[k] = bx.w;
            ar[k] = area_lds[r];
            if (keys[r] != 0ULL) alive |= (1u << k);
        }
        for (int it = 0; it < MAX_DET; ++it) {
            unsigned long long bal = __ballot(alive != 0u);
            if (bal == 0ULL) {
                if (lane == 0) {
                    sel_score[bc * MAX_DET + it] = NEGV;
                    sel_box[bc * MAX_DET + it] = make_float4(0.f, 0.f, 0.f, 0.f);
                }
                continue;
            }
            int lw = __ffsll((unsigned long long)bal) - 1;
            unsigned aw = __shfl(alive, lw);
            int bit = __ffs(aw) - 1;
            int widx = lw * 8 + bit;
            float4 wb = box_lds[widx];       // broadcast LDS read
            float warea = area_lds[widx];
            if (lane == 0) {
                unsigned long long wk = keys[widx];
                sel_score[bc * MAX_DET + it] = deordf((unsigned)(wk >> 32));
                sel_box[bc * MAX_DET + it] = wb;
            }
            unsigned sup = 0u;
            #pragma unroll
            for (int k = 0; k < 8; ++k) {
                float yy1 = fmaxf(wb.x, y1[k]);
                float xx1 = fmaxf(wb.y, x1[k]);
                float yy2 = fminf(wb.z, y2[k]);
                float xx2 = fminf(wb.w, x2[k]);
                float ih = fmaxf(yy2 - yy1, 0.0f);
                float iw = fmaxf(xx2 - xx1, 0.0f);
                float inter = ih * iw;
                float denom = ((warea + ar[k]) - inter) + 1e-8f;
                if ((double)inter > IOU_CMP_C * (double)denom) sup |= (1u << k);
            }
            alive &= ~sup;
            if (lane == lw) alive &= ~(1u << bit);   // reference: idxs == j always suppressed
        }
    }
}

// ---------------- Final: per-batch merge of 90 descending lists, top-100 (LDS-staged keys) ----------------
__global__ __launch_bounds__(256) void k_merge(const float* __restrict__ sel_score,
                                               const float4* __restrict__ sel_box,
                                               float* __restrict__ out) {
    int b = blockIdx.x;
    int tid = threadIdx.x;
    __shared__ unsigned long long lkeys[NC * MAX_DET];   // 72 KB
    __shared__ unsigned long long win[MAX_DET];
    const float* ss = sel_score + b * NC * MAX_DET;

    for (int i = tid; i < NC * MAX_DET; i += 256)
        lkeys[i] = mkkey(ss[i], (unsigned)i);
    __syncthreads();

    if (tid < 64) {
        int lane = tid;
        int r1 = 0, r2 = 0;
        unsigned long long k1 = lkeys[lane * MAX_DET];                      // classes 0..63
        unsigned long long k2 = (lane < 26) ? lkeys[(64 + lane) * MAX_DET] : 0ULL; // 64..89
        for (int it = 0; it < MAX_DET; ++it) {
            unsigned long long w = k1 > k2 ? k1 : k2;
            for (int off = 1; off < 64; off <<= 1) {
                unsigned long long o = __shfl_xor(w, off);
                if (o > w) w = o;
            }
            if (lane == 0) win[it] = w;
            if (k1 == w) { r1++; k1 = (r1 < MAX_DET) ? lkeys[lane * MAX_DET + r1] : 0ULL; }
            else if (lane < 26 && k2 == w) { r2++; k2 = (r2 < MAX_DET) ? lkeys[(64 + lane) * MAX_DET + r2] : 0ULL; }
        }

        int nv = 0;
        for (int t = lane; t < MAX_DET; t += 64) {
            unsigned long long w = win[t];
            unsigned flat = 0xFFFFFFFFu - (unsigned)(w & 0xFFFFFFFFu);
            float sdec = deordf((unsigned)(w >> 32));
            bool valid = (w != 0ULL) && (sdec >= SCORE_THR);
            float4 bx = make_float4(0.f, 0.f, 0.f, 0.f);
            float so = 0.0f; int cls = 0;
            if (valid) {
                bx = sel_box[b * NC * MAX_DET + flat];
                so = sdec;
                cls = (int)(flat / MAX_DET);
                nv++;
            }
            float* ob = out + (size_t)(b * MAX_DET + t) * 4;
            ob[0] = bx.x; ob[1] = bx.y; ob[2] = bx.z; ob[3] = bx.w;
            out[NB * MAX_DET * 4 + b * MAX_DET + t] = so;
            out[NB * MAX_DET * 5 + b * MAX_DET + t] = (float)cls;
        }
        for (int off = 1; off < 64; off <<= 1) nv += __shfl_xor(nv, off);
        if (lane == 0) out[NB * MAX_DET * 6 + b] = (float)nv;
    }
}

extern "C" void kernel_launch(void* const* d_in, const int* in_sizes, int n_in,
                              void* d_out, int out_size, void* d_ws, size_t ws_size,
                              hipStream_t stream) {
    const float* boxes = (const float*)d_in[0];
    const float* scores = (const float*)d_in[1];
    float* out = (float*)d_out;

    char* ws = (char*)d_ws;
    size_t off = 0;
    auto alloc = [&](size_t bytes) -> void* {
        void* p = ws + off;
        off = (off + bytes + 255) & ~(size_t)255;
        return p;
    };
    unsigned* cnt = (unsigned*)alloc((size_t)NBC * CNT_STRIDE * 4);
    unsigned* ovf = (unsigned*)alloc((size_t)NBC * 4);
    unsigned long long* buf = (unsigned long long*)alloc((size_t)NBC * CAP * 8);
    float* sel_score = (float*)alloc((size_t)NBC * MAX_DET * 4);
    float4* sel_box = (float4*)alloc((size_t)NBC * MAX_DET * 16);

    k_zero<<<(NBC * CNT_STRIDE / 4 + 255) / 256, 256, 0, stream>>>((uint4*)cnt, (uint4*)ovf);
    k_collect<<<NB * NCHUNK, 512, 0, stream>>>(scores, cnt, ovf, buf);
    k_sortnms<<<NBC, 256, 0, stream>>>(scores, boxes, cnt, ovf, buf, sel_score, sel_box);
    k_merge<<<NB, 256, 0, stream>>>(sel_score, sel_box, out);
}

// Round 7
// 193.857 us; speedup vs baseline: 1.0148x; 1.0148x over previous
//
#include <hip/hip_runtime.h>

#define NB 8
#define NN 100000
#define NC 90
#define SCORE_THR 0.05f
#define IOU_THR 0.5f
#define MAX_DET 100
#define PRE_NMS_K 512
#define NEGV -1000000000.0f
#define T0 0.9925f
#define CAP 1024
#define NBC (NB * NC)
#define CNT_STRIDE 16   // u32 words per counter (64B line padding)
#define CHUNK 1024
#define NCHUNK 98       // ceil(100000/1024)
#define LCAP 32
// Exact: RN(inter/denom) > 0.5f  <=>  (double)inter > (0.5+2^-26)*(double)denom
// (denom has 24-bit mantissa; (1+2^-25) has 26 bits; product <= 50 bits -> exact in f64)
#define IOU_CMP_C 0x1.0000008p-1

typedef float f32x4 __attribute__((ext_vector_type(4)));

__device__ __forceinline__ unsigned ordf(float s) {
    unsigned u = __float_as_uint(s);
    return (u & 0x80000000u) ? ~u : (u | 0x80000000u);
}
__device__ __forceinline__ float deordf(unsigned o) {
    return (o & 0x80000000u) ? __uint_as_float(o ^ 0x80000000u) : __uint_as_float(~o);
}
__device__ __forceinline__ unsigned long long mkkey(float s, unsigned idx) {
    return ((unsigned long long)ordf(s) << 32) | (unsigned long long)(0xFFFFFFFFu - idx);
}

// ---------------- zero counters + overflow flags ----------------
__global__ __launch_bounds__(256) void k_zero(uint4* __restrict__ cnt4, uint4* __restrict__ ovf4) {
    unsigned i = blockIdx.x * 256u + threadIdx.x;
    if (i < (NBC * CNT_STRIDE) / 4) cnt4[i] = make_uint4(0u, 0u, 0u, 0u);
    if (i < NBC / 4) ovf4[i] = make_uint4(0u, 0u, 0u, 0u);
}

// ---------------- Pass 1: streaming scan (cached loads, 3-deep exact unroll), LDS staging ----------------
__global__ __launch_bounds__(512) void k_collect(const float* __restrict__ scores,
                                                 unsigned* __restrict__ cnt,
                                                 unsigned* __restrict__ ovf,
                                                 unsigned long long* __restrict__ buf) {
    __shared__ unsigned long long lst[NC][LCAP + 1];
    __shared__ unsigned lcnt[NC];
    int b = blockIdx.x / NCHUNK;
    int chunk = blockIdx.x - b * NCHUNK;
    int n0 = chunk * CHUNK;
    const f32x4* base4 = reinterpret_cast<const f32x4*>(scores + ((size_t)b * NN + n0) * NC);

    for (int i = threadIdx.x; i < NC; i += 512) lcnt[i] = 0u;
    __syncthreads();

    auto process = [&](f32x4 v, int idx) {
        #pragma unroll
        for (int e = 0; e < 4; ++e) {
            float s = v[e];
            if (s >= T0) {
                int local = 4 * idx + e;
                int c = local % NC;
                int n = n0 + local / NC;
                unsigned slot = atomicAdd(&lcnt[c], 1u);
                if (slot < LCAP) lst[c][slot] = mkkey(s, (unsigned)n);
                else atomicOr(&ovf[b * NC + c], 1u);   // ~never
            }
        }
    };

    if (chunk != NCHUNK - 1) {
        // full chunk: nf4 = 1024*90/4 = 23040 = 15 * (3*512): exact 3-deep, no guards
        for (int i0 = (int)threadIdx.x; i0 < 23040; i0 += 1536) {
            f32x4 v0 = base4[i0];
            f32x4 v1 = base4[i0 + 512];
            f32x4 v2 = base4[i0 + 1024];
            process(v0, i0);
            process(v1, i0 + 512);
            process(v2, i0 + 1024);
        }
    } else {
        int ncount = NN - n0;
        int nf4 = (ncount * NC) >> 2;
        for (int i = (int)threadIdx.x; i < nf4; i += 512) {
            f32x4 v = base4[i];
            process(v, i);
        }
    }
    __syncthreads();

    if (threadIdx.x < NC) {
        int c = threadIdx.x;
        unsigned k = lcnt[c]; if (k > LCAP) k = LCAP;
        if (k) {
            int bc = b * NC + c;
            unsigned basep = atomicAdd(&cnt[(size_t)bc * CNT_STRIDE], k);
            if (basep + k > CAP) atomicOr(&ovf[bc], 1u);
            unsigned lim = (basep + k <= CAP) ? k : (basep < CAP ? CAP - basep : 0u);
            for (unsigned j = 0; j < lim; ++j)
                buf[(size_t)bc * CAP + basep + j] = lst[c][j];
        }
    }
}

// ---------------- Fused: (rebuild-if-bad) -> bitonic sort 1024 -> pointer-walk NMS (wave 0) ----------------
__global__ __launch_bounds__(256) void k_sortnms(const float* __restrict__ scores,
                                                 const float* __restrict__ boxes,
                                                 const unsigned* __restrict__ cnt,
                                                 const unsigned* __restrict__ ovf,
                                                 const unsigned long long* __restrict__ buf,
                                                 float* __restrict__ sel_score,
                                                 float4* __restrict__ sel_box) {
    #pragma clang fp contract(off)
    int bc = blockIdx.x;
    int tid = threadIdx.x;
    __shared__ unsigned long long keys[CAP];
    // box/area (good path, post-sort) overlay hist (bad path, pre-sort) — never live together
    __shared__ __align__(16) unsigned char gmem[PRE_NMS_K * 16 + PRE_NMS_K * 4];
    float4* box_lds = (float4*)gmem;
    float* area_lds = (float*)(gmem + PRE_NMS_K * 16);
    unsigned* hist = (unsigned*)gmem;
    __shared__ unsigned s_lcnt;
    __shared__ float s_cut;

    unsigned K = cnt[(size_t)bc * CNT_STRIDE];
    bool bad = (ovf[bc] != 0u) || (K < (unsigned)PRE_NMS_K) || (K > CAP);

    if (bad) {
        // exact rebuild directly into LDS (never fires for this input)
        int b = bc / NC, c = bc - (bc / NC) * NC;
        for (int i = tid; i < 1024; i += 256) hist[i] = 0u;
        if (tid == 0) s_lcnt = 0u;
        __syncthreads();
        for (int n = tid; n < NN; n += 256) {
            float s = scores[((size_t)b * NN + n) * NC + c];
            if (s >= SCORE_THR) {
                int bin = (int)(s * 1024.0f);
                bin = bin < 0 ? 0 : (bin > 1023 ? 1023 : bin);
                atomicAdd(&hist[bin], 1u);
            }
        }
        __syncthreads();
        if (tid == 0) {
            unsigned tot = 0;
            for (int i = 0; i < 1024; ++i) tot += hist[i];
            unsigned target = tot < (unsigned)PRE_NMS_K ? tot : (unsigned)PRE_NMS_K;
            float cut = 3.0e38f;
            if (target > 0) {
                unsigned cum = 0; int t = 1023;
                for (; t >= 0; --t) { cum += hist[t]; if (cum >= target) break; }
                cut = (float)t / 1024.0f;
                if (cut < SCORE_THR) cut = SCORE_THR;
            }
            s_cut = cut;
        }
        __syncthreads();
        float cut = s_cut;
        for (int n = tid; n < NN; n += 256) {
            float s = scores[((size_t)b * NN + n) * NC + c];
            if (s >= SCORE_THR && s >= cut) {
                unsigned slot = atomicAdd(&s_lcnt, 1u);
                if (slot < CAP) keys[slot] = mkkey(s, (unsigned)n);
            }
        }
        __syncthreads();
        K = s_lcnt; if (K > CAP) K = CAP;
        for (unsigned i = K + tid; i < CAP; i += 256) keys[i] = 0ULL;
        __syncthreads();
    } else {
        for (unsigned i = tid; i < CAP; i += 256)
            keys[i] = (i < K) ? buf[(size_t)bc * CAP + i] : 0ULL;
    }

    // bitonic sort, descending. Barrier only when data crosses 64-element (wave-owned)
    // blocks: j<64 stages are wave-synchronous (wave64 lockstep, in-order LDS pipe).
    bool prev_big = false;
    for (unsigned k2 = 2; k2 <= CAP; k2 <<= 1) {
        for (unsigned j = k2 >> 1; j; j >>= 1) {
            bool big = (j >= 64);
            if (big || prev_big) __syncthreads();
            #pragma unroll
            for (unsigned ii = 0; ii < 4; ++ii) {
                unsigned i = tid + ii * 256u;
                unsigned ixj = i ^ j;
                if (ixj > i) {
                    unsigned long long a = keys[i], bv = keys[ixj];
                    bool desc = ((i & k2) == 0);
                    if (desc ? (a < bv) : (a > bv)) { keys[i] = bv; keys[ixj] = a; }
                }
            }
            prev_big = big;
        }
    }
    __syncthreads();

    // gather boxes + areas for the (sorted) top-512
    int b = bc / NC;
    for (int r = tid; r < PRE_NMS_K; r += 256) {
        unsigned long long key = keys[r];
        float4 bx = make_float4(0.f, 0.f, 0.f, 0.f);
        if (key != 0ULL) {
            unsigned n = 0xFFFFFFFFu - (unsigned)(key & 0xFFFFFFFFu);
            bx = *reinterpret_cast<const float4*>(boxes + ((size_t)b * NN + n) * 4);
        }
        box_lds[r] = bx;
        area_lds[r] = (bx.z - bx.x) * (bx.w - bx.y);
    }
    __syncthreads();

    // NMS on wave 0: sorted keys => winner = first alive index (pointer walk via ballot)
    if (tid < 64) {
        int lane = tid;
        float y1[8], x1[8], y2[8], x2[8], ar[8];
        unsigned alive = 0u;                 // 8 candidates per lane, contiguous: r = lane*8+k
        #pragma unroll
        for (int k = 0; k < 8; ++k) {
            int r = lane * 8 + k;
            float4 bx = box_lds[r];
            y1[k] = bx.x; x1[k] = bx.y; y2[k] = bx.z; x2[k] = bx.w;
            ar[k] = area_lds[r];
            if (keys[r] != 0ULL) alive |= (1u << k);
        }
        for (int it = 0; it < MAX_DET; ++it) {
            unsigned long long bal = __ballot(alive != 0u);
            if (bal == 0ULL) {
                if (lane == 0) {
                    sel_score[bc * MAX_DET + it] = NEGV;
                    sel_box[bc * MAX_DET + it] = make_float4(0.f, 0.f, 0.f, 0.f);
                }
                continue;
            }
            int lw = __ffsll((unsigned long long)bal) - 1;
            unsigned aw = __shfl(alive, lw);
            int bit = __ffs(aw) - 1;
            int widx = lw * 8 + bit;
            float4 wb = box_lds[widx];       // broadcast LDS read
            float warea = area_lds[widx];
            if (lane == 0) {
                unsigned long long wk = keys[widx];
                sel_score[bc * MAX_DET + it] = deordf((unsigned)(wk >> 32));
                sel_box[bc * MAX_DET + it] = wb;
            }
            unsigned sup = 0u;
            #pragma unroll
            for (int k = 0; k < 8; ++k) {
                float yy1 = fmaxf(wb.x, y1[k]);
                float xx1 = fmaxf(wb.y, x1[k]);
                float yy2 = fminf(wb.z, y2[k]);
                float xx2 = fminf(wb.w, x2[k]);
                float ih = fmaxf(yy2 - yy1, 0.0f);
                float iw = fmaxf(xx2 - xx1, 0.0f);
                float inter = ih * iw;
                float denom = ((warea + ar[k]) - inter) + 1e-8f;
                if ((double)inter > IOU_CMP_C * (double)denom) sup |= (1u << k);
            }
            alive &= ~sup;
            if (lane == lw) alive &= ~(1u << bit);   // reference: idxs == j always suppressed
        }
    }
}

// ---------------- Final: per-batch merge of 90 descending lists, top-100 (LDS-staged keys) ----------------
__global__ __launch_bounds__(256) void k_merge(const float* __restrict__ sel_score,
                                               const float4* __restrict__ sel_box,
                                               float* __restrict__ out) {
    int b = blockIdx.x;
    int tid = threadIdx.x;
    __shared__ unsigned long long lkeys[NC * MAX_DET];   // 72 KB
    __shared__ unsigned long long win[MAX_DET];
    const float* ss = sel_score + b * NC * MAX_DET;

    for (int i = tid; i < NC * MAX_DET; i += 256)
        lkeys[i] = mkkey(ss[i], (unsigned)i);
    __syncthreads();

    if (tid < 64) {
        int lane = tid;
        int r1 = 0, r2 = 0;
        unsigned long long k1 = lkeys[lane * MAX_DET];                      // classes 0..63
        unsigned long long k2 = (lane < 26) ? lkeys[(64 + lane) * MAX_DET] : 0ULL; // 64..89
        for (int it = 0; it < MAX_DET; ++it) {
            unsigned long long w = k1 > k2 ? k1 : k2;
            for (int off = 1; off < 64; off <<= 1) {
                unsigned long long o = __shfl_xor(w, off);
                if (o > w) w = o;
            }
            if (lane == 0) win[it] = w;
            if (k1 == w) { r1++; k1 = (r1 < MAX_DET) ? lkeys[lane * MAX_DET + r1] : 0ULL; }
            else if (lane < 26 && k2 == w) { r2++; k2 = (r2 < MAX_DET) ? lkeys[(64 + lane) * MAX_DET + r2] : 0ULL; }
        }

        int nv = 0;
        for (int t = lane; t < MAX_DET; t += 64) {
            unsigned long long w = win[t];
            unsigned flat = 0xFFFFFFFFu - (unsigned)(w & 0xFFFFFFFFu);
            float sdec = deordf((unsigned)(w >> 32));
            bool valid = (w != 0ULL) && (sdec >= SCORE_THR);
            float4 bx = make_float4(0.f, 0.f, 0.f, 0.f);
            float so = 0.0f; int cls = 0;
            if (valid) {
                bx = sel_box[b * NC * MAX_DET + flat];
                so = sdec;
                cls = (int)(flat / MAX_DET);
                nv++;
            }
            float* ob = out + (size_t)(b * MAX_DET + t) * 4;
            ob[0] = bx.x; ob[1] = bx.y; ob[2] = bx.z; ob[3] = bx.w;
            out[NB * MAX_DET * 4 + b * MAX_DET + t] = so;
            out[NB * MAX_DET * 5 + b * MAX_DET + t] = (float)cls;
        }
        for (int off = 1; off < 64; off <<= 1) nv += __shfl_xor(nv, off);
        if (lane == 0) out[NB * MAX_DET * 6 + b] = (float)nv;
    }
}

extern "C" void kernel_launch(void* const* d_in, const int* in_sizes, int n_in,
                              void* d_out, int out_size, void* d_ws, size_t ws_size,
                              hipStream_t stream) {
    const float* boxes = (const float*)d_in[0];
    const float* scores = (const float*)d_in[1];
    float* out = (float*)d_out;

    char* ws = (char*)d_ws;
    size_t off = 0;
    auto alloc = [&](size_t bytes) -> void* {
        void* p = ws + off;
        off = (off + bytes + 255) & ~(size_t)255;
        return p;
    };
    unsigned* cnt = (unsigned*)alloc((size_t)NBC * CNT_STRIDE * 4);
    unsigned* ovf = (unsigned*)alloc((size_t)NBC * 4);
    unsigned long long* buf = (unsigned long long*)alloc((size_t)NBC * CAP * 8);
    float* sel_score = (float*)alloc((size_t)NBC * MAX_DET * 4);
    float4* sel_box = (float4*)alloc((size_t)NBC * MAX_DET * 16);

    k_zero<<<(NBC * CNT_STRIDE / 4 + 255) / 256, 256, 0, stream>>>((uint4*)cnt, (uint4*)ovf);
    k_collect<<<NB * NCHUNK, 512, 0, stream>>>(scores, cnt, ovf, buf);
    k_sortnms<<<NBC, 256, 0, stream>>>(scores, boxes, cnt, ovf, buf, sel_score, sel_box);
    k_merge<<<NB, 256, 0, stream>>>(sel_score, sel_box, out);
}

// Round 8
// 185.692 us; speedup vs baseline: 1.0594x; 1.0440x over previous
//
#include <hip/hip_runtime.h>

#define NB 8
#define NN 100000
#define NC 90
#define SCORE_THR 0.05f
#define IOU_THR 0.5f
#define MAX_DET 100
#define PRE_NMS_K 512
#define NEGV -1000000000.0f
#define T0 0.9925f
#define CAP 1024
#define NBC (NB * NC)
#define CHUNK 1024
#define NCHUNK 98       // ceil(100000/1024)
#define LCAP 32         // max staged keys per (class, chunk); P(exceed) ~ 1e-12
// Exact: RN(inter/denom) > 0.5f  <=>  (double)inter > (0.5+2^-26)*(double)denom
// (denom has 24-bit mantissa; (1+2^-25) has 26 bits; product <= 50 bits -> exact in f64)
#define IOU_CMP_C 0x1.0000008p-1

typedef float f32x4 __attribute__((ext_vector_type(4)));

__device__ __forceinline__ unsigned ordf(float s) {
    unsigned u = __float_as_uint(s);
    return (u & 0x80000000u) ? ~u : (u | 0x80000000u);
}
__device__ __forceinline__ float deordf(unsigned o) {
    return (o & 0x80000000u) ? __uint_as_float(o ^ 0x80000000u) : __uint_as_float(~o);
}
__device__ __forceinline__ unsigned long long mkkey(float s, unsigned idx) {
    return ((unsigned long long)ordf(s) << 32) | (unsigned long long)(0xFFFFFFFFu - idx);
}

// ---------------- Pass 1: streaming scan, per-class LDS staging, FIXED-SLOT output ----------------
// No global atomics, no pre-zeroed counters: block (b,chunk) owns slots
// buf2[(bc*NCHUNK+chunk)*LCAP ...] and count cnt2[bc*NCHUNK+chunk]. Fully deterministic.
__global__ __launch_bounds__(512) void k_collect(const float* __restrict__ scores,
                                                 unsigned* __restrict__ cnt2,
                                                 unsigned long long* __restrict__ buf2) {
    __shared__ unsigned long long lst[NC][LCAP + 1];
    __shared__ unsigned lcnt[NC];
    int b = blockIdx.x / NCHUNK;
    int chunk = blockIdx.x - b * NCHUNK;
    int n0 = chunk * CHUNK;
    int ncount = NN - n0; if (ncount > CHUNK) ncount = CHUNK;
    int nf4 = (ncount * NC) >> 2;            // ncount*90 always divisible by 4
    const f32x4* base4 = reinterpret_cast<const f32x4*>(scores + ((size_t)b * NN + n0) * NC);

    for (int i = threadIdx.x; i < NC; i += 512) lcnt[i] = 0u;
    __syncthreads();

    for (int i = (int)threadIdx.x; i < nf4; i += 512) {
        f32x4 v = base4[i];
        #pragma unroll
        for (int e = 0; e < 4; ++e) {
            float s = v[e];
            if (s >= T0) {
                int local = 4 * i + e;
                int c = local % NC;
                int n = n0 + local / NC;
                unsigned slot = atomicAdd(&lcnt[c], 1u);
                if (slot < LCAP) lst[c][slot] = mkkey(s, (unsigned)n);
            }
        }
    }
    __syncthreads();

    if (threadIdx.x < NC) {
        int c = threadIdx.x;
        int bc = b * NC + c;
        unsigned count = lcnt[c];
        cnt2[(size_t)bc * NCHUNK + chunk] = count;     // raw count; >LCAP routes to rebuild
        unsigned k = count > LCAP ? LCAP : count;
        unsigned long long* dst = buf2 + ((size_t)bc * NCHUNK + chunk) * LCAP;
        for (unsigned j = 0; j < k; ++j) dst[j] = lst[c][j];
    }
}

// ---------------- Fused: gather fixed slots -> (rebuild-if-bad) -> bitonic 1024 -> NMS ----------------
__global__ __launch_bounds__(256) void k_sortnms(const float* __restrict__ scores,
                                                 const float* __restrict__ boxes,
                                                 const unsigned* __restrict__ cnt2,
                                                 const unsigned long long* __restrict__ buf2,
                                                 float* __restrict__ sel_score,
                                                 float4* __restrict__ sel_box) {
    #pragma clang fp contract(off)
    int bc = blockIdx.x;
    int tid = threadIdx.x;
    __shared__ unsigned long long keys[CAP];
    // box/area (good path, post-sort) overlay hist (bad path, pre-sort) — never live together
    __shared__ __align__(16) unsigned char gmem[PRE_NMS_K * 16 + PRE_NMS_K * 4];
    float4* box_lds = (float4*)gmem;
    float* area_lds = (float*)(gmem + PRE_NMS_K * 16);
    unsigned* hist = (unsigned*)gmem;
    __shared__ unsigned segc[NCHUNK];
    __shared__ unsigned sego[NCHUNK + 1];
    __shared__ unsigned s_bad;
    __shared__ unsigned s_lcnt;
    __shared__ float s_cut;

    if (tid == 0) s_bad = 0u;
    if (tid < NCHUNK) segc[tid] = cnt2[(size_t)bc * NCHUNK + tid];
    __syncthreads();
    if (tid < NCHUNK && segc[tid] > LCAP) atomicOr(&s_bad, 1u);
    if (tid == 0) {
        unsigned a = 0;
        for (int p = 0; p < NCHUNK; ++p) {
            sego[p] = a;
            unsigned k = segc[p]; if (k > LCAP) k = LCAP;
            a += k;
        }
        sego[NCHUNK] = a;
    }
    __syncthreads();
    unsigned K = sego[NCHUNK];
    bool bad = (s_bad != 0u) || (K < (unsigned)PRE_NMS_K) || (K > CAP);

    if (bad) {
        // exact rebuild directly into LDS (never fires for this input)
        int b = bc / NC, c = bc - (bc / NC) * NC;
        for (int i = tid; i < 1024; i += 256) hist[i] = 0u;
        if (tid == 0) s_lcnt = 0u;
        __syncthreads();
        for (int n = tid; n < NN; n += 256) {
            float s = scores[((size_t)b * NN + n) * NC + c];
            if (s >= SCORE_THR) {
                int bin = (int)(s * 1024.0f);
                bin = bin < 0 ? 0 : (bin > 1023 ? 1023 : bin);
                atomicAdd(&hist[bin], 1u);
            }
        }
        __syncthreads();
        if (tid == 0) {
            unsigned tot = 0;
            for (int i = 0; i < 1024; ++i) tot += hist[i];
            unsigned target = tot < (unsigned)PRE_NMS_K ? tot : (unsigned)PRE_NMS_K;
            float cut = 3.0e38f;
            if (target > 0) {
                unsigned cum = 0; int t = 1023;
                for (; t >= 0; --t) { cum += hist[t]; if (cum >= target) break; }
                cut = (float)t / 1024.0f;
                if (cut < SCORE_THR) cut = SCORE_THR;
            }
            s_cut = cut;
        }
        __syncthreads();
        float cut = s_cut;
        for (int n = tid; n < NN; n += 256) {
            float s = scores[((size_t)b * NN + n) * NC + c];
            if (s >= SCORE_THR && s >= cut) {
                unsigned slot = atomicAdd(&s_lcnt, 1u);
                if (slot < CAP) keys[slot] = mkkey(s, (unsigned)n);
            }
        }
        __syncthreads();
        K = s_lcnt; if (K > CAP) K = CAP;
        for (unsigned i = K + tid; i < CAP; i += 256) keys[i] = 0ULL;
        __syncthreads();
    } else {
        // coalesced slot read (98*32 contiguous u64), predicated compact into LDS
        const unsigned long long* src = buf2 + (size_t)bc * NCHUNK * LCAP;
        for (int slot = tid; slot < NCHUNK * LCAP; slot += 256) {
            int p = slot >> 5, j = slot & 31;
            if ((unsigned)j < segc[p]) keys[sego[p] + j] = src[slot];
        }
        __syncthreads();
        for (unsigned i = K + tid; i < CAP; i += 256) keys[i] = 0ULL;
    }

    // bitonic sort, descending. Barrier only when data crosses 64-element (wave-owned)
    // blocks: j<64 stages are wave-synchronous (wave64 lockstep, in-order LDS pipe).
    bool prev_big = true;   // barrier before first stage (gather wrote cross-wave)
    for (unsigned k2 = 2; k2 <= CAP; k2 <<= 1) {
        for (unsigned j = k2 >> 1; j; j >>= 1) {
            bool big = (j >= 64);
            if (big || prev_big) __syncthreads();
            #pragma unroll
            for (unsigned ii = 0; ii < 4; ++ii) {
                unsigned i = tid + ii * 256u;
                unsigned ixj = i ^ j;
                if (ixj > i) {
                    unsigned long long a = keys[i], bv = keys[ixj];
                    bool desc = ((i & k2) == 0);
                    if (desc ? (a < bv) : (a > bv)) { keys[i] = bv; keys[ixj] = a; }
                }
            }
            prev_big = big;
        }
    }
    __syncthreads();

    // gather boxes + areas for the (sorted) top-512
    int b = bc / NC;
    for (int r = tid; r < PRE_NMS_K; r += 256) {
        unsigned long long key = keys[r];
        float4 bx = make_float4(0.f, 0.f, 0.f, 0.f);
        if (key != 0ULL) {
            unsigned n = 0xFFFFFFFFu - (unsigned)(key & 0xFFFFFFFFu);
            bx = *reinterpret_cast<const float4*>(boxes + ((size_t)b * NN + n) * 4);
        }
        box_lds[r] = bx;
        area_lds[r] = (bx.z - bx.x) * (bx.w - bx.y);
    }
    __syncthreads();

    // NMS on wave 0: sorted keys => winner = first alive index (pointer walk via ballot)
    if (tid < 64) {
        int lane = tid;
        float y1[8], x1[8], y2[8], x2[8], ar[8];
        unsigned alive = 0u;                 // 8 candidates per lane, contiguous: r = lane*8+k
        #pragma unroll
        for (int k = 0; k < 8; ++k) {
            int r = lane * 8 + k;
            float4 bx = box_lds[r];
            y1[k] = bx.x; x1[k] = bx.y; y2[k] = bx.z; x2[k] = bx.w;
            ar[k] = area_lds[r];
            if (keys[r] != 0ULL) alive |= (1u << k);
        }
        for (int it = 0; it < MAX_DET; ++it) {
            unsigned long long bal = __ballot(alive != 0u);
            if (bal == 0ULL) {
                if (lane == 0) {
                    sel_score[bc * MAX_DET + it] = NEGV;
                    sel_box[bc * MAX_DET + it] = make_float4(0.f, 0.f, 0.f, 0.f);
                }
                continue;
            }
            int lw = __ffsll((unsigned long long)bal) - 1;
            unsigned aw = __shfl(alive, lw);
            int bit = __ffs(aw) - 1;
            int widx = lw * 8 + bit;
            float4 wb = box_lds[widx];       // broadcast LDS read
            float warea = area_lds[widx];
            if (lane == 0) {
                unsigned long long wk = keys[widx];
                sel_score[bc * MAX_DET + it] = deordf((unsigned)(wk >> 32));
                sel_box[bc * MAX_DET + it] = wb;
            }
            unsigned sup = 0u;
            #pragma unroll
            for (int k = 0; k < 8; ++k) {
                float yy1 = fmaxf(wb.x, y1[k]);
                float xx1 = fmaxf(wb.y, x1[k]);
                float yy2 = fminf(wb.z, y2[k]);
                float xx2 = fminf(wb.w, x2[k]);
                float ih = fmaxf(yy2 - yy1, 0.0f);
                float iw = fmaxf(xx2 - xx1, 0.0f);
                float inter = ih * iw;
                float denom = ((warea + ar[k]) - inter) + 1e-8f;
                if ((double)inter > IOU_CMP_C * (double)denom) sup |= (1u << k);
            }
            alive &= ~sup;
            if (lane == lw) alive &= ~(1u << bit);   // reference: idxs == j always suppressed
        }
    }
}

// ---------------- Final: per-batch merge of 90 descending lists, top-100 (LDS-staged keys) ----------------
__global__ __launch_bounds__(256) void k_merge(const float* __restrict__ sel_score,
                                               const float4* __restrict__ sel_box,
                                               float* __restrict__ out) {
    int b = blockIdx.x;
    int tid = threadIdx.x;
    __shared__ unsigned long long lkeys[NC * MAX_DET];   // 72 KB
    __shared__ unsigned long long win[MAX_DET];
    const float* ss = sel_score + b * NC * MAX_DET;

    for (int i = tid; i < NC * MAX_DET; i += 256)
        lkeys[i] = mkkey(ss[i], (unsigned)i);
    __syncthreads();

    if (tid < 64) {
        int lane = tid;
        int r1 = 0, r2 = 0;
        unsigned long long k1 = lkeys[lane * MAX_DET];                      // classes 0..63
        unsigned long long k2 = (lane < 26) ? lkeys[(64 + lane) * MAX_DET] : 0ULL; // 64..89
        for (int it = 0; it < MAX_DET; ++it) {
            unsigned long long w = k1 > k2 ? k1 : k2;
            for (int off = 1; off < 64; off <<= 1) {
                unsigned long long o = __shfl_xor(w, off);
                if (o > w) w = o;
            }
            if (lane == 0) win[it] = w;
            if (k1 == w) { r1++; k1 = (r1 < MAX_DET) ? lkeys[lane * MAX_DET + r1] : 0ULL; }
            else if (lane < 26 && k2 == w) { r2++; k2 = (r2 < MAX_DET) ? lkeys[(64 + lane) * MAX_DET + r2] : 0ULL; }
        }

        int nv = 0;
        for (int t = lane; t < MAX_DET; t += 64) {
            unsigned long long w = win[t];
            unsigned flat = 0xFFFFFFFFu - (unsigned)(w & 0xFFFFFFFFu);
            float sdec = deordf((unsigned)(w >> 32));
            bool valid = (w != 0ULL) && (sdec >= SCORE_THR);
            float4 bx = make_float4(0.f, 0.f, 0.f, 0.f);
            float so = 0.0f; int cls = 0;
            if (valid) {
                bx = sel_box[b * NC * MAX_DET + flat];
                so = sdec;
                cls = (int)(flat / MAX_DET);
                nv++;
            }
            float* ob = out + (size_t)(b * MAX_DET + t) * 4;
            ob[0] = bx.x; ob[1] = bx.y; ob[2] = bx.z; ob[3] = bx.w;
            out[NB * MAX_DET * 4 + b * MAX_DET + t] = so;
            out[NB * MAX_DET * 5 + b * MAX_DET + t] = (float)cls;
        }
        for (int off = 1; off < 64; off <<= 1) nv += __shfl_xor(nv, off);
        if (lane == 0) out[NB * MAX_DET * 6 + b] = (float)nv;
    }
}

extern "C" void kernel_launch(void* const* d_in, const int* in_sizes, int n_in,
                              void* d_out, int out_size, void* d_ws, size_t ws_size,
                              hipStream_t stream) {
    const float* boxes = (const float*)d_in[0];
    const float* scores = (const float*)d_in[1];
    float* out = (float*)d_out;

    char* ws = (char*)d_ws;
    size_t off = 0;
    auto alloc = [&](size_t bytes) -> void* {
        void* p = ws + off;
        off = (off + bytes + 255) & ~(size_t)255;
        return p;
    };
    unsigned* cnt2 = (unsigned*)alloc((size_t)NBC * NCHUNK * 4);
    unsigned long long* buf2 = (unsigned long long*)alloc((size_t)NBC * NCHUNK * LCAP * 8);
    float* sel_score = (float*)alloc((size_t)NBC * MAX_DET * 4);
    float4* sel_box = (float4*)alloc((size_t)NBC * MAX_DET * 16);

    k_collect<<<NB * NCHUNK, 512, 0, stream>>>(scores, cnt2, buf2);
    k_sortnms<<<NBC, 256, 0, stream>>>(scores, boxes, cnt2, buf2, sel_score, sel_box);
    k_merge<<<NB, 256, 0, stream>>>(sel_score, sel_box, out);
}

// Round 9
// 169.362 us; speedup vs baseline: 1.1615x; 1.0964x over previous
//
#include <hip/hip_runtime.h>

#define NB 8
#define NN 100000
#define NC 90
#define SCORE_THR 0.05f
#define IOU_THR 0.5f
#define MAX_DET 100
#define PRE_NMS_K 512
#define NEGV -1000000000.0f
#define T0 0.9925f
#define CAP 1024
#define NBC (NB * NC)
#define CHUNK 1024
#define NCHUNK 98       // ceil(100000/1024)
#define LCAP 32         // max staged keys per (class, chunk); P(exceed) ~ 1e-12
#define NT 512          // sortnms/collect block size
// Exact: RN(inter/denom) > 0.5f  <=>  (double)inter > (0.5+2^-26)*(double)denom
// (denom has 24-bit mantissa; (1+2^-25) has 26 bits; product <= 50 bits -> exact in f64)
#define IOU_CMP_C 0x1.0000008p-1

typedef float f32x4 __attribute__((ext_vector_type(4)));

__device__ __forceinline__ unsigned ordf(float s) {
    unsigned u = __float_as_uint(s);
    return (u & 0x80000000u) ? ~u : (u | 0x80000000u);
}
__device__ __forceinline__ float deordf(unsigned o) {
    return (o & 0x80000000u) ? __uint_as_float(o ^ 0x80000000u) : __uint_as_float(~o);
}
__device__ __forceinline__ unsigned long long mkkey(float s, unsigned idx) {
    return ((unsigned long long)ordf(s) << 32) | (unsigned long long)(0xFFFFFFFFu - idx);
}

// ---------------- Pass 1: streaming scan, per-class LDS staging, FIXED-SLOT output ----------------
// No global atomics, no pre-zeroed counters: block (b,chunk) owns slots
// buf2[(bc*NCHUNK+chunk)*LCAP ...] and count cnt2[bc*NCHUNK+chunk]. Fully deterministic.
__global__ __launch_bounds__(NT) void k_collect(const float* __restrict__ scores,
                                                unsigned* __restrict__ cnt2,
                                                unsigned long long* __restrict__ buf2) {
    __shared__ unsigned long long lst[NC][LCAP + 1];
    __shared__ unsigned lcnt[NC];
    int b = blockIdx.x / NCHUNK;
    int chunk = blockIdx.x - b * NCHUNK;
    int n0 = chunk * CHUNK;
    int ncount = NN - n0; if (ncount > CHUNK) ncount = CHUNK;
    int nf4 = (ncount * NC) >> 2;            // ncount*90 always divisible by 4
    const f32x4* base4 = reinterpret_cast<const f32x4*>(scores + ((size_t)b * NN + n0) * NC);

    for (int i = threadIdx.x; i < NC; i += NT) lcnt[i] = 0u;
    __syncthreads();

    for (int i = (int)threadIdx.x; i < nf4; i += NT) {
        f32x4 v = base4[i];
        #pragma unroll
        for (int e = 0; e < 4; ++e) {
            float s = v[e];
            if (s >= T0) {
                int local = 4 * i + e;
                int c = local % NC;
                int n = n0 + local / NC;
                unsigned slot = atomicAdd(&lcnt[c], 1u);
                if (slot < LCAP) lst[c][slot] = mkkey(s, (unsigned)n);
            }
        }
    }
    __syncthreads();

    // cooperative coalesced flush of all class lists
    for (int idx = threadIdx.x; idx < NC * LCAP; idx += NT) {
        int c = idx >> 5;                  // LCAP == 32
        int j = idx & (LCAP - 1);
        unsigned cc = lcnt[c];
        unsigned k = cc > LCAP ? LCAP : cc;
        if ((unsigned)j < k)
            buf2[((size_t)(b * NC + c) * NCHUNK + chunk) * LCAP + j] = lst[c][j];
    }
    if (threadIdx.x < NC) {
        int c = threadIdx.x;
        cnt2[(size_t)(b * NC + c) * NCHUNK + chunk] = lcnt[c];   // raw; >LCAP routes to rebuild
    }
}

// ---------------- Fused: gather fixed slots -> (rebuild-if-bad) -> bitonic 1024 -> NMS ----------------
__global__ __launch_bounds__(NT) void k_sortnms(const float* __restrict__ scores,
                                                const float* __restrict__ boxes,
                                                const unsigned* __restrict__ cnt2,
                                                const unsigned long long* __restrict__ buf2,
                                                float* __restrict__ sel_score,
                                                float4* __restrict__ sel_box) {
    #pragma clang fp contract(off)
    int bc = blockIdx.x;
    int tid = threadIdx.x;
    __shared__ unsigned long long keys[CAP];
    // box/area (good path, post-sort) overlay hist (bad path, pre-sort) — never live together
    __shared__ __align__(16) unsigned char gmem[PRE_NMS_K * 16 + PRE_NMS_K * 4];
    float4* box_lds = (float4*)gmem;
    float* area_lds = (float*)(gmem + PRE_NMS_K * 16);
    unsigned* hist = (unsigned*)gmem;
    __shared__ unsigned segc[NCHUNK];
    __shared__ unsigned sego[NCHUNK + 1];
    __shared__ unsigned s_bad;
    __shared__ unsigned s_lcnt;
    __shared__ float s_cut;

    if (tid == 0) s_bad = 0u;
    if (tid < NCHUNK) segc[tid] = cnt2[(size_t)bc * NCHUNK + tid];
    __syncthreads();
    if (tid < NCHUNK && segc[tid] > LCAP) atomicOr(&s_bad, 1u);
    if (tid == 0) {
        unsigned a = 0;
        for (int p = 0; p < NCHUNK; ++p) {
            sego[p] = a;
            unsigned k = segc[p]; if (k > LCAP) k = LCAP;
            a += k;
        }
        sego[NCHUNK] = a;
    }
    __syncthreads();
    unsigned K = sego[NCHUNK];
    bool bad = (s_bad != 0u) || (K < (unsigned)PRE_NMS_K) || (K > CAP);

    if (bad) {
        // exact rebuild directly into LDS (never fires for this input)
        int b = bc / NC, c = bc - (bc / NC) * NC;
        for (int i = tid; i < 1024; i += NT) hist[i] = 0u;
        if (tid == 0) s_lcnt = 0u;
        __syncthreads();
        for (int n = tid; n < NN; n += NT) {
            float s = scores[((size_t)b * NN + n) * NC + c];
            if (s >= SCORE_THR) {
                int bin = (int)(s * 1024.0f);
                bin = bin < 0 ? 0 : (bin > 1023 ? 1023 : bin);
                atomicAdd(&hist[bin], 1u);
            }
        }
        __syncthreads();
        if (tid == 0) {
            unsigned tot = 0;
            for (int i = 0; i < 1024; ++i) tot += hist[i];
            unsigned target = tot < (unsigned)PRE_NMS_K ? tot : (unsigned)PRE_NMS_K;
            float cut = 3.0e38f;
            if (target > 0) {
                unsigned cum = 0; int t = 1023;
                for (; t >= 0; --t) { cum += hist[t]; if (cum >= target) break; }
                cut = (float)t / 1024.0f;
                if (cut < SCORE_THR) cut = SCORE_THR;
            }
            s_cut = cut;
        }
        __syncthreads();
        float cut = s_cut;
        for (int n = tid; n < NN; n += NT) {
            float s = scores[((size_t)b * NN + n) * NC + c];
            if (s >= SCORE_THR && s >= cut) {
                unsigned slot = atomicAdd(&s_lcnt, 1u);
                if (slot < CAP) keys[slot] = mkkey(s, (unsigned)n);
            }
        }
        __syncthreads();
        K = s_lcnt; if (K > CAP) K = CAP;
        for (unsigned i = K + tid; i < CAP; i += NT) keys[i] = 0ULL;
        __syncthreads();
    } else {
        // coalesced slot read (98*32 contiguous u64), predicated compact into LDS
        const unsigned long long* src = buf2 + (size_t)bc * NCHUNK * LCAP;
        for (int slot = tid; slot < NCHUNK * LCAP; slot += NT) {
            int p = slot >> 5, j = slot & 31;
            if ((unsigned)j < segc[p]) keys[sego[p] + j] = src[slot];
        }
        __syncthreads();
        for (unsigned i = K + tid; i < CAP; i += NT) keys[i] = 0ULL;
    }

    // bitonic sort, descending: 512 threads, one compare-swap pair per thread per stage.
    // i = ((t & ~(j-1))<<1) | (t & (j-1)), partner = i|j. Each 64-aligned key block B is
    // handled only by threads [B*32, B*32+32) ⊂ wave B>>1 (mapping independent of j), so
    // j<64 stages are wave-synchronous: barrier only when j>=64 or the prior stage was.
    bool prev_big = true;   // barrier before first stage (gather wrote cross-wave)
    for (unsigned k2 = 2; k2 <= CAP; k2 <<= 1) {
        for (unsigned j = k2 >> 1; j; j >>= 1) {
            bool big = (j >= 64);
            if (big || prev_big) __syncthreads();
            unsigned low = (unsigned)tid & (j - 1u);
            unsigned i = (((unsigned)tid & ~(j - 1u)) << 1) | low;
            unsigned ixj = i | j;
            unsigned long long a = keys[i], bv = keys[ixj];
            bool desc = ((i & k2) == 0);
            if (desc ? (a < bv) : (a > bv)) { keys[i] = bv; keys[ixj] = a; }
            prev_big = big;
        }
    }
    __syncthreads();

    // gather boxes + areas for the (sorted) top-512
    int b = bc / NC;
    for (int r = tid; r < PRE_NMS_K; r += NT) {
        unsigned long long key = keys[r];
        float4 bx = make_float4(0.f, 0.f, 0.f, 0.f);
        if (key != 0ULL) {
            unsigned n = 0xFFFFFFFFu - (unsigned)(key & 0xFFFFFFFFu);
            bx = *reinterpret_cast<const float4*>(boxes + ((size_t)b * NN + n) * 4);
        }
        box_lds[r] = bx;
        area_lds[r] = (bx.z - bx.x) * (bx.w - bx.y);
    }
    __syncthreads();

    // NMS on wave 0: sorted keys => winner = first alive index (pointer walk via ballot)
    if (tid < 64) {
        int lane = tid;
        float y1[8], x1[8], y2[8], x2[8], ar[8];
        unsigned alive = 0u;                 // 8 candidates per lane, contiguous: r = lane*8+k
        #pragma unroll
        for (int k = 0; k < 8; ++k) {
            int r = lane * 8 + k;
            float4 bx = box_lds[r];
            y1[k] = bx.x; x1[k] = bx.y; y2[k] = bx.z; x2[k] = bx.w;
            ar[k] = area_lds[r];
            if (keys[r] != 0ULL) alive |= (1u << k);
        }
        for (int it = 0; it < MAX_DET; ++it) {
            unsigned long long bal = __ballot(alive != 0u);
            if (bal == 0ULL) {
                if (lane == 0) {
                    sel_score[bc * MAX_DET + it] = NEGV;
                    sel_box[bc * MAX_DET + it] = make_float4(0.f, 0.f, 0.f, 0.f);
                }
                continue;
            }
            int lw = __ffsll((unsigned long long)bal) - 1;
            unsigned aw = __shfl(alive, lw);
            int bit = __ffs(aw) - 1;
            int widx = lw * 8 + bit;
            float4 wb = box_lds[widx];       // broadcast LDS read
            float warea = area_lds[widx];
            if (lane == 0) {
                unsigned long long wk = keys[widx];
                sel_score[bc * MAX_DET + it] = deordf((unsigned)(wk >> 32));
                sel_box[bc * MAX_DET + it] = wb;
            }
            unsigned sup = 0u;
            #pragma unroll
            for (int k = 0; k < 8; ++k) {
                float yy1 = fmaxf(wb.x, y1[k]);
                float xx1 = fmaxf(wb.y, x1[k]);
                float yy2 = fminf(wb.z, y2[k]);
                float xx2 = fminf(wb.w, x2[k]);
                float ih = fmaxf(yy2 - yy1, 0.0f);
                float iw = fmaxf(xx2 - xx1, 0.0f);
                float inter = ih * iw;
                float denom = ((warea + ar[k]) - inter) + 1e-8f;
                if ((double)inter > IOU_CMP_C * (double)denom) sup |= (1u << k);
            }
            alive &= ~sup;
            if (lane == lw) alive &= ~(1u << bit);   // reference: idxs == j always suppressed
        }
    }
}

// ---------------- Final: per-batch merge of 90 descending lists, top-100 (LDS-staged keys) ----------------
__global__ __launch_bounds__(256) void k_merge(const float* __restrict__ sel_score,
                                               const float4* __restrict__ sel_box,
                                               float* __restrict__ out) {
    int b = blockIdx.x;
    int tid = threadIdx.x;
    __shared__ unsigned long long lkeys[NC * MAX_DET];   // 72 KB
    __shared__ unsigned long long win[MAX_DET];
    const float* ss = sel_score + b * NC * MAX_DET;

    for (int i = tid; i < NC * MAX_DET; i += 256)
        lkeys[i] = mkkey(ss[i], (unsigned)i);
    __syncthreads();

    if (tid < 64) {
        int lane = tid;
        int r1 = 0, r2 = 0;
        unsigned long long k1 = lkeys[lane * MAX_DET];                      // classes 0..63
        unsigned long long k2 = (lane < 26) ? lkeys[(64 + lane) * MAX_DET] : 0ULL; // 64..89
        for (int it = 0; it < MAX_DET; ++it) {
            unsigned long long w = k1 > k2 ? k1 : k2;
            for (int off = 1; off < 64; off <<= 1) {
                unsigned long long o = __shfl_xor(w, off);
                if (o > w) w = o;
            }
            if (lane == 0) win[it] = w;
            if (k1 == w) { r1++; k1 = (r1 < MAX_DET) ? lkeys[lane * MAX_DET + r1] : 0ULL; }
            else if (lane < 26 && k2 == w) { r2++; k2 = (r2 < MAX_DET) ? lkeys[(64 + lane) * MAX_DET + r2] : 0ULL; }
        }

        int nv = 0;
        for (int t = lane; t < MAX_DET; t += 64) {
            unsigned long long w = win[t];
            unsigned flat = 0xFFFFFFFFu - (unsigned)(w & 0xFFFFFFFFu);
            float sdec = deordf((unsigned)(w >> 32));
            bool valid = (w != 0ULL) && (sdec >= SCORE_THR);
            float4 bx = make_float4(0.f, 0.f, 0.f, 0.f);
            float so = 0.0f; int cls = 0;
            if (valid) {
                bx = sel_box[b * NC * MAX_DET + flat];
                so = sdec;
                cls = (int)(flat / MAX_DET);
                nv++;
            }
            float* ob = out + (size_t)(b * MAX_DET + t) * 4;
            ob[0] = bx.x; ob[1] = bx.y; ob[2] = bx.z; ob[3] = bx.w;
            out[NB * MAX_DET * 4 + b * MAX_DET + t] = so;
            out[NB * MAX_DET * 5 + b * MAX_DET + t] = (float)cls;
        }
        for (int off = 1; off < 64; off <<= 1) nv += __shfl_xor(nv, off);
        if (lane == 0) out[NB * MAX_DET * 6 + b] = (float)nv;
    }
}

extern "C" void kernel_launch(void* const* d_in, const int* in_sizes, int n_in,
                              void* d_out, int out_size, void* d_ws, size_t ws_size,
                              hipStream_t stream) {
    const float* boxes = (const float*)d_in[0];
    const float* scores = (const float*)d_in[1];
    float* out = (float*)d_out;

    char* ws = (char*)d_ws;
    size_t off = 0;
    auto alloc = [&](size_t bytes) -> void* {
        void* p = ws + off;
        off = (off + bytes + 255) & ~(size_t)255;
        return p;
    };
    unsigned* cnt2 = (unsigned*)alloc((size_t)NBC * NCHUNK * 4);
    unsigned long long* buf2 = (unsigned long long*)alloc((size_t)NBC * NCHUNK * LCAP * 8);
    float* sel_score = (float*)alloc((size_t)NBC * MAX_DET * 4);
    float4* sel_box = (float4*)alloc((size_t)NBC * MAX_DET * 16);

    k_collect<<<NB * NCHUNK, NT, 0, stream>>>(scores, cnt2, buf2);
    k_sortnms<<<NBC, NT, 0, stream>>>(scores, boxes, cnt2, buf2, sel_score, sel_box);
    k_merge<<<NB, 256, 0, stream>>>(sel_score, sel_box, out);
}